// Round 6
// baseline (585.432 us; speedup 1.0000x reference)
//
#include <hip/hip_runtime.h>

#define F1260 1260

__device__ __forceinline__ float leakyf(float x) { return x >= 0.f ? x : 0.2f * x; }
__device__ __forceinline__ float eluf(float x) { return x > 0.f ? x : expm1f(x); }
__device__ __forceinline__ float sigmoidf(float x) { return 1.f / (1.f + __expf(-x)); }

// ws float-offset map (params < 60 KB):
//   0..1259   : fsum per flat-feature f      (atomic accum, memset to 0)
//   1280..2539: fsq per flat-feature f
//   2560: scale[42]     2624: shift[42]
//   2688: adjn[7][49]   (6 GAT1 heads + GAT2 head0)
//   3072: WB[180][24]   (per k=c*30+tt: [0..17]=GAT1 hh*3+{si,sj,we},
//                        [18..20]={a2si[tt],a2sj[tt],W2[tt][0]}, 3 pad)
//   13600: bias[84] (b_ih+b_hh)  13700: Wout[147]  13860: bout[7]
// byte 65536: res f32 [252][N]  (rows 0..125: GAT1 v*18+q; 126..251: GAT2 trios)

// ---------------- kA: BN stats, float4-coalesced, 32 rows/block ----------------
__global__ __launch_bounds__(320) void kA_stats(const float* __restrict__ x,
                                                float* __restrict__ ws, int N) {
    const int t = threadIdx.x;
    if (t >= 315) return;
    const int n0 = blockIdx.x * 32;
    const int f0 = t * 4;
    float s[4] = {0.f, 0.f, 0.f, 0.f}, q[4] = {0.f, 0.f, 0.f, 0.f};
#pragma unroll 8
    for (int i = 0; i < 32; ++i) {
        const float4 a = *(const float4*)(x + (size_t)(n0 + i) * F1260 + f0);
        s[0] += a.x; q[0] += a.x * a.x;
        s[1] += a.y; q[1] += a.y * a.y;
        s[2] += a.z; q[2] += a.z * a.z;
        s[3] += a.w; q[3] += a.w * a.w;
    }
#pragma unroll
    for (int j = 0; j < 4; ++j) {
        atomicAdd(&ws[f0 + j], s[j]);
        atomicAdd(&ws[1280 + f0 + j], q[j]);
    }
}

// ---------------- kB: finalize BN, adjacency norm, weight folds ----------------
__global__ __launch_bounds__(1024) void kB_setup(
        const float* __restrict__ bn_gamma, const float* __restrict__ bn_beta,
        const float* __restrict__ W1, const float* __restrict__ a1, const float* __restrict__ B1,
        const float* __restrict__ W2, const float* __restrict__ a2, const float* __restrict__ B2,
        const float* __restrict__ b_ih, const float* __restrict__ b_hh,
        const float* __restrict__ W_out, const float* __restrict__ b_out,
        float* __restrict__ ws, int N) {
    __shared__ float sf[1260], sq[1260];
    const int t = threadIdx.x;
    const int HH[6] = {0, 3, 6, 10, 13, 16};
    const int EH[6] = {0, 3, 6, 0, 3, 6};

    for (int i = t; i < F1260; i += 1024) { sf[i] = ws[i]; sq[i] = ws[1280 + i]; }
    __syncthreads();

    // per-channel BN scale/shift; channel ch = v*6 + c; flat f = c*210 + tt*7 + v
    if (t < 42) {
        const int v = t / 6, c = t % 6;
        float s = 0.f, q = 0.f;
        for (int tt = 0; tt < 30; ++tt) {
            const int f = c * 210 + tt * 7 + v;
            s += sf[f];
            q += sq[f];
        }
        const float cnt = 30.f * (float)N;
        const float mean = s / cnt;
        const float var = q / cnt - mean * mean;
        const float sc = bn_gamma[t] * rsqrtf(var + 1e-5f);
        ws[2560 + t] = sc;
        ws[2624 + t] = bn_beta[t] - mean * sc;
    }
    // normalized adjacency: 6 GAT1 heads + GAT2 head0
    if (t >= 64 && t < 71) {
        const int idx = t - 64;
        const float* Bp = (idx < 6) ? (B1 + HH[idx] * 49) : B2;
        float* op = ws + 2688 + idx * 49;
        float adj[49];
        for (int i = 0; i < 49; ++i) adj[i] = Bp[i];
        for (int i = 0; i < 7; ++i) adj[i * 8] += 1.f;
        float mn = adj[0], mx = adj[0];
        for (int i = 1; i < 49; ++i) { mn = fminf(mn, adj[i]); mx = fmaxf(mx, adj[i]); }
        const float inv = 1.f / (mx - mn);
        float rinv[7];
        for (int i = 0; i < 7; ++i) {
            float rs = 0.f;
            for (int j = 0; j < 7; ++j) { adj[i * 7 + j] = (adj[i * 7 + j] - mn) * inv; rs += adj[i * 7 + j]; }
            rinv[i] = rsqrtf(rs);
        }
        for (int i = 0; i < 7; ++i)
            for (int j = 0; j < 7; ++j)
                op[i * 7 + j] = adj[i * 7 + j] * rinv[i] * rinv[j];
    }
    // WB: fold a1 into W1 for the 6 live heads, repacked per-k
    for (int task = t; task < 6 * 180; task += 1024) {
        const int hh = task / 180, k = task % 180;
        const int h = HH[hh];
        const float* Wp = W1 + ((size_t)h * 180 + k) * 9;
        float si = 0.f, sj = 0.f;
        for (int e = 0; e < 9; ++e) {
            const float w = Wp[e];
            si += w * a1[h * 18 + e];
            sj += w * a1[h * 18 + 9 + e];
        }
        ws[3072 + k * 24 + hh * 3 + 0] = si;
        ws[3072 + k * 24 + hh * 3 + 1] = sj;
        ws[3072 + k * 24 + hh * 3 + 2] = Wp[EH[hh]];
    }
    // WA2 slots (replicated per c): head 0 of l2, f=0 column kept
    if (t < 30) {
        const float* Wp = W2 + t * 10;
        float si = 0.f, sj = 0.f;
        for (int f = 0; f < 10; ++f) {
            const float w = Wp[f];
            si += w * a2[f];
            sj += w * a2[10 + f];
        }
        for (int c = 0; c < 6; ++c) {
            const int k = c * 30 + t;
            ws[3072 + k * 24 + 18] = si;
            ws[3072 + k * 24 + 19] = sj;
            ws[3072 + k * 24 + 20] = Wp[0];
        }
    }
    if (t < 84) ws[13600 + t] = b_ih[t] + b_hh[t];
    if (t < 147) ws[13700 + t] = W_out[t];
    if (t < 7) ws[13860 + t] = b_out[t];
}

// ---------------- kC1: dots -> global res, reg-prefetch pipeline ----------------
// 256 threads, 32 samples/block. LDS = 26880 B only -> 5 blocks/CU.
__global__ __launch_bounds__(256) void kC1_dots(const float* __restrict__ x,
        const float* __restrict__ ws, float* __restrict__ res, int N) {
    __shared__ float stage[32 * 210];
    const int t = threadIdx.x;
    const int n0 = blockIdx.x * 32;
    const int v = t >> 5, nl = t & 31;
    const int n = n0 + nl;
    const float* xbase = x + (size_t)n0 * F1260;
    const float* WB = ws + 3072;

    float s1[18];
#pragma unroll
    for (int i = 0; i < 18; ++i) s1[i] = 0.f;

    float2 pf[14];
    auto loadc = [&](int c) {
#pragma unroll
        for (int k = 0; k < 14; ++k) {
            const int idx = t + (k << 8);
            if (idx < 3360) {
                const int row = idx / 105;
                const int col = idx - row * 105;
                pf[k] = *(const float2*)(xbase + (size_t)row * F1260 + c * 210 + col * 2);
            }
        }
    };

    loadc(0);
    for (int c = 0; c < 6; ++c) {
        // write prefetched chunk into stage
#pragma unroll
        for (int k = 0; k < 14; ++k) {
            const int idx = t + (k << 8);
            if (idx < 3360) {
                const int row = idx / 105;
                const int col = idx - row * 105;
                *(float2*)(stage + row * 210 + col * 2) = pf[k];
            }
        }
        __syncthreads();
        if (c < 5) loadc(c + 1);   // fire-and-forget into regs; overlaps compute
        if (v < 7) {
            const float sc = ws[2560 + v * 6 + c];
            const float sh = ws[2624 + v * 6 + c];
            const float* xr = stage + nl * 210 + v;
            const float* wb = WB + (c * 30) * 24;
            float g0 = 0.f, g1 = 0.f, g2 = 0.f;
#pragma unroll
            for (int tt = 0; tt < 30; ++tt) {
                const float a = xr[tt * 7] * sc + sh;
                const float* w = wb + tt * 24;
#pragma unroll
                for (int q = 0; q < 18; ++q) s1[q] += a * w[q];
                g0 += a * w[18];
                g1 += a * w[19];
                g2 += a * w[20];
            }
            const size_t qb = (size_t)(126 + (v * 6 + c) * 3) * N + n;
            res[qb] = g0;
            res[qb + N] = g1;
            res[qb + 2 * (size_t)N] = g2;
        }
        __syncthreads();   // stage dead before next overwrite
    }
    if (v < 7) {
#pragma unroll
        for (int q = 0; q < 18; ++q)
            res[(size_t)(v * 18 + q) * N + n] = s1[q];
    }
}

// ---------------- kC2: attention + LSTM tail, thread = sample ----------------
__global__ __launch_bounds__(64, 2) void kC2_tail(const float* __restrict__ res,
        const float* __restrict__ ws, const float* __restrict__ Wih,
        float* __restrict__ outp, int N) {
    const int n = blockIdx.x * 64 + threadIdx.x;
    const float* rp = res + n;
    float xs[84];

    // ----- GAT2 head 0 (softmax over channels) first: frees 126 regs early -----
    {
        float si2[42], sj2[42], wh0[42];
#pragma unroll
        for (int m = 0; m < 42; ++m) {
            si2[m] = rp[(size_t)(126 + 3 * m) * N];
            sj2[m] = rp[(size_t)(127 + 3 * m) * N];
            wh0[m] = rp[(size_t)(128 + 3 * m) * N];
        }
        float h2[42];   // [c][i]
#pragma unroll
        for (int i = 0; i < 42; ++i) h2[i] = 0.f;
#pragma unroll
        for (int i = 0; i < 7; ++i) {
#pragma unroll
            for (int j = 0; j < 7; ++j) {
                float s[6];
                float m = -1e30f;
#pragma unroll
                for (int c = 0; c < 6; ++c) {
                    s[c] = leakyf(si2[i * 6 + c] + sj2[j * 6 + c]);
                    m = fmaxf(m, s[c]);
                }
                float den = 0.f;
#pragma unroll
                for (int c = 0; c < 6; ++c) { s[c] = __expf(s[c] - m); den += s[c]; }
                const float rd = 1.f / den;
#pragma unroll
                for (int c = 0; c < 6; ++c)
                    h2[c * 7 + i] += wh0[j * 6 + c] * s[c] * rd;
            }
        }
        const float* An2 = ws + 2688 + 6 * 49;
#pragma unroll
        for (int c = 0; c < 6; ++c)
#pragma unroll
            for (int vv = 0; vv < 7; ++vv) {
                float r = 0.f;
#pragma unroll
                for (int u = 0; u < 7; ++u) r += h2[c * 7 + u] * An2[u * 7 + vv];
                xs[42 + c * 7 + vv] = eluf(r);
            }
    }

    // ----- GAT1: 6 live heads, one at a time -----
#pragma unroll
    for (int hh = 0; hh < 6; ++hh) {
        float si[7], sj[7], we[7];
#pragma unroll
        for (int vv = 0; vv < 7; ++vv) {
            const size_t b = (size_t)(vv * 18 + hh * 3) * N;
            si[vv] = rp[b];
            sj[vv] = rp[b + N];
            we[vv] = rp[b + 2 * (size_t)N];
        }
        float mxsj = sj[0];
#pragma unroll
        for (int j = 1; j < 7; ++j) mxsj = fmaxf(mxsj, sj[j]);
        float p[7];
#pragma unroll
        for (int i = 0; i < 7; ++i) {
            const float m = leakyf(si[i] + mxsj);   // leaky monotonic -> row max
            float den = 0.f, num = 0.f;
#pragma unroll
            for (int j = 0; j < 7; ++j) {
                const float w = __expf(leakyf(si[i] + sj[j]) - m);
                den += w;
                num += w * we[j];
            }
            p[i] = num / den;
        }
        const float* An = ws + 2688 + hh * 49;
#pragma unroll
        for (int i = 0; i < 7; ++i) {
            float r = 0.f;
#pragma unroll
            for (int k = 0; k < 7; ++k) r += An[i * 7 + k] * p[k];
            xs[hh * 7 + i] = eluf(r);
        }
    }

    // ----- LSTM step 0 (h0=c0=0) + output projection -----
    const float* bias = ws + 13600;
    float h1[21];
#pragma unroll 3
    for (int gi = 0; gi < 21; ++gi) {
        float ga = bias[gi], gg = bias[42 + gi], go = bias[63 + gi];
        const float4* wa = (const float4*)(Wih + gi * 84);
        const float4* wg = (const float4*)(Wih + (42 + gi) * 84);
        const float4* wo = (const float4*)(Wih + (63 + gi) * 84);
#pragma unroll
        for (int k4 = 0; k4 < 21; ++k4) {
            const float4 fa = wa[k4], fg = wg[k4], fo = wo[k4];
            const float x0 = xs[k4 * 4 + 0], x1 = xs[k4 * 4 + 1];
            const float x2 = xs[k4 * 4 + 2], x3 = xs[k4 * 4 + 3];
            ga += x0 * fa.x + x1 * fa.y + x2 * fa.z + x3 * fa.w;
            gg += x0 * fg.x + x1 * fg.y + x2 * fg.z + x3 * fg.w;
            go += x0 * fo.x + x1 * fo.y + x2 * fo.z + x3 * fo.w;
        }
        const float c1 = sigmoidf(ga) * tanhf(gg);
        h1[gi] = sigmoidf(go) * tanhf(c1);
    }
    const float* Wout = ws + 13700;
#pragma unroll
    for (int j = 0; j < 7; ++j) {
        float r = ws[13860 + j];
#pragma unroll
        for (int m = 0; m < 21; ++m) r += h1[m] * Wout[j * 21 + m];
        outp[(size_t)n * 7 + j] = r;
    }
}

extern "C" void kernel_launch(void* const* d_in, const int* in_sizes, int n_in,
                              void* d_out, int out_size, void* d_ws, size_t ws_size,
                              hipStream_t stream) {
    const int N = in_sizes[0] / F1260;

    const float* x        = (const float*)d_in[0];
    const float* bn_gamma = (const float*)d_in[1];
    const float* bn_beta  = (const float*)d_in[2];
    const float* W1       = (const float*)d_in[3];
    const float* a1       = (const float*)d_in[4];
    const float* B1       = (const float*)d_in[5];
    const float* W2       = (const float*)d_in[6];
    const float* a2       = (const float*)d_in[7];
    const float* B2       = (const float*)d_in[8];
    const float* W_ih     = (const float*)d_in[9];
    // d_in[10] = W_hh unused (h0 = 0 -> only LSTM step 0 matters)
    const float* b_ih     = (const float*)d_in[11];
    const float* b_hh     = (const float*)d_in[12];
    const float* W_out    = (const float*)d_in[13];
    const float* b_out    = (const float*)d_in[14];

    float* wsf = (float*)d_ws;
    float* res = (float*)((char*)d_ws + 65536);   // 252*N floats = 33 MB @ N=32768

    hipMemsetAsync(d_ws, 0, 2560 * sizeof(float), stream);   // zero fsum/fsq

    kA_stats<<<dim3(N / 32), dim3(320), 0, stream>>>(x, wsf, N);
    kB_setup<<<dim3(1), dim3(1024), 0, stream>>>(bn_gamma, bn_beta, W1, a1, B1,
                                                 W2, a2, B2, b_ih, b_hh,
                                                 W_out, b_out, wsf, N);
    kC1_dots<<<dim3(N / 32), dim3(256), 0, stream>>>(x, wsf, res, N);
    kC2_tail<<<dim3(N / 64), dim3(64), 0, stream>>>(res, wsf, W_ih, (float*)d_out, N);
}